// Round 8
// baseline (429.082 us; speedup 1.0000x reference)
//
#include <hip/hip_runtime.h>

// BjorckLinear: out = X @ bjorck10(W)^T
//   X: [131072, 512] f32, W: [512, 512] f32, out: [131072, 512] f32
//
// R8: (a) Bjorck reverted to R4's proven 20-launch k_mm2 (hidden-converter and
//     all fusion attempts measured slower); final update writes only Wh.
//     (b) k_big: whole 64x512 X-tile staged to LDS ONCE (f32->bf16, padded
//     row stride -> conflict-free b128 reads); k-loop stages only W from L2
//     (4 glds/wave, covered by compute) -> no HBM latency on the k-loop path.

using bf16x8 = __attribute__((ext_vector_type(8))) short;
using f32x4  = __attribute__((ext_vector_type(4))) float;
using u16x8  = __attribute__((ext_vector_type(8))) unsigned short;

#define DI 512
#define MFMA16(a, b, c) __builtin_amdgcn_mfma_f32_16x16x32_bf16(a, b, c, 0, 0, 0)
#define SXS 520   // sX row stride (bf16): 512 + 8 pad -> bank = 4*(row+chunk)%32

__device__ __forceinline__ unsigned short f2bf(float f) {
  unsigned int u = __builtin_bit_cast(unsigned int, f);
  u += 0x7FFFu + ((u >> 16) & 1u);   // RNE
  return (unsigned short)(u >> 16);
}
__device__ __forceinline__ float bf2f(unsigned short h) {
  unsigned int u = ((unsigned int)h) << 16;
  return __builtin_bit_cast(float, u);
}

// ---- initial split: W f32 -> f32 master + hi/lo bf16 (+ transposed) ----
__global__ void k_split(const float* __restrict__ W, float* __restrict__ Wm,
                        unsigned short* __restrict__ Wh, unsigned short* __restrict__ Wl,
                        unsigned short* __restrict__ WTh, unsigned short* __restrict__ WTl) {
  int idx = blockIdx.x * blockDim.x + threadIdx.x;
  int m = idx >> 9, i = idx & 511;
  float w = W[idx];
  Wm[idx] = w;
  unsigned short h  = f2bf(w);
  unsigned short lo = f2bf(w - bf2f(h));
  Wh[idx] = h; Wl[idx] = lo;
  WTh[i * DI + m] = h; WTl[i * DI + m] = lo;
}

// ---- 512x512 NT GEMM: wave per (16x16 tile, K-half); LDS pair-reduce ----
// C[m][n] = sum_k A'[m][k] * B'[n][k]  (A'=Ah+Al, B'=Bh+Bl; l*l dropped)
// mode 0: C -> hi/lo bf16 (Oh, Ol)
// mode 1: Wnew = 1.5*Wm_in - 0.5*C -> f32 + hi/lo + transposed hi/lo
// mode 2: like mode 1 but writes ONLY Oh (final iteration)
__global__ __launch_bounds__(256) void k_mm2(
    const unsigned short* __restrict__ Ah, const unsigned short* __restrict__ Al,
    const unsigned short* __restrict__ Bh, const unsigned short* __restrict__ Bl,
    int mode,
    const float* __restrict__ Wm_in, float* __restrict__ Wm_out,
    unsigned short* __restrict__ Oh, unsigned short* __restrict__ Ol,
    unsigned short* __restrict__ OTh, unsigned short* __restrict__ OTl) {
  const int tid = threadIdx.x;
  const int l = tid & 63, lw = tid >> 6;
  const int wid = (blockIdx.x << 2) | lw;     // 0..2047
  const int tile = wid >> 1, half = wid & 1;  // 1024 tiles x 2 K-halves
  const int m0 = (tile >> 5) << 4, n0 = (tile & 31) << 4;
  const int kb = half << 8;
  const int lm = l & 15, lk = l >> 4;
  const int ra = (m0 + lm) * DI + kb + (lk << 3);
  const int rb = (n0 + lm) * DI + kb + (lk << 3);

  __shared__ f32x4 red[2][64];
  const int pr = lw >> 1;

  f32x4 a0{}, a1{}, a2{}, a3{}, a4{}, a5{};
#pragma unroll
  for (int k0 = 0; k0 < 256; k0 += 64) {
    bf16x8 ah0 = *(const bf16x8*)&Ah[ra + k0];
    bf16x8 al0 = *(const bf16x8*)&Al[ra + k0];
    bf16x8 bh0 = *(const bf16x8*)&Bh[rb + k0];
    bf16x8 bl0 = *(const bf16x8*)&Bl[rb + k0];
    bf16x8 ah1 = *(const bf16x8*)&Ah[ra + k0 + 32];
    bf16x8 al1 = *(const bf16x8*)&Al[ra + k0 + 32];
    bf16x8 bh1 = *(const bf16x8*)&Bh[rb + k0 + 32];
    bf16x8 bl1 = *(const bf16x8*)&Bl[rb + k0 + 32];
    a0 = MFMA16(ah0, bh0, a0);
    a1 = MFMA16(ah0, bl0, a1);
    a2 = MFMA16(al0, bh0, a2);
    a3 = MFMA16(ah1, bh1, a3);
    a4 = MFMA16(ah1, bl1, a4);
    a5 = MFMA16(al1, bh1, a5);
  }
  f32x4 acc = (a0 + a1) + (a2 + a3) + (a4 + a5);

  if (half) red[pr][l] = acc;
  __syncthreads();
  if (!half) {
    acc += red[pr][l];
    const int r0 = m0 + (lk << 2);
    const int cn = n0 + lm;
#pragma unroll
    for (int r = 0; r < 4; ++r) {
      const int gm = r0 + r, gn = cn;
      const float v = acc[r];
      if (mode == 0) {
        unsigned short h = f2bf(v);
        Oh[gm * DI + gn] = h;
        Ol[gm * DI + gn] = f2bf(v - bf2f(h));
      } else if (mode == 1) {
        const float wn = 1.5f * Wm_in[gm * DI + gn] - 0.5f * v;
        Wm_out[gm * DI + gn] = wn;
        unsigned short h = f2bf(wn), lo = f2bf(wn - bf2f(h));
        Oh[gm * DI + gn] = h;   Ol[gm * DI + gn] = lo;
        OTh[gn * DI + gm] = h;  OTl[gn * DI + gm] = lo;
      } else {   // mode 2: final — only bf16-hi needed by k_big
        const float wn = 1.5f * Wm_in[gm * DI + gn] - 0.5f * v;
        Oh[gm * DI + gn] = f2bf(wn);
      }
    }
  }
}

// ---------------- direct-to-LDS helper ----------------
#if defined(__has_builtin)
#if __has_builtin(__builtin_amdgcn_global_load_lds)
#define HAVE_GLDS 1
#endif
#endif

#ifdef HAVE_GLDS
__device__ __forceinline__ void gl2lds16(const unsigned short* g, unsigned short* lds) {
  __builtin_amdgcn_global_load_lds(
      (const __attribute__((address_space(1))) void*)g,
      (__attribute__((address_space(3))) void*)lds, 16, 0, 0);
}
#endif

// ---------------- big GEMM: out = bf16(X) @ Wp^T ----------------
// grid 2048, block 512 (8 waves), BM=64, BN=512 (X read once), BK=32.
// Phase A: whole 64x512 X-tile -> LDS (f32 load, coalesced chunk-interleave,
//          cvt bf16, padded-stride conflict-free store). ONE time.
// Phase B: 16 k-steps; only W staged (4 glds/wave from L2, double-buffered);
//          10 ds_read_b128 + 16 MFMA per wave per step; one barrier/step.
// Wave grid 2m x 4n: wave owns 32 rows x 128 cols; swapped MFMA operands ->
// lane holds out[gm][gn..gn+3] -> dwordx4 stores.
__global__ __launch_bounds__(512, 1) void k_big(
    const float* __restrict__ X, const unsigned short* __restrict__ Wp,
    float* __restrict__ out) {
  __shared__ unsigned short sX[64 * SXS];   // 65 KB, row stride 520
  __shared__ unsigned short sB[2][512 * 32]; // 2 x 32 KB
  const int tid = threadIdx.x;
  const int wv = tid >> 6, l = tid & 63;
  const int lm = l & 15, lk = l >> 4;
  const int ck = lk ^ ((lm >> 1) & 3);        // sB swizzled read chunk
  const int wm = wv >> 2, wn = wv & 3;        // 2m x 4n wave roles
  const int rowbase = blockIdx.x << 6;

  // W staging: wave wv stages rows [64*wv, 64*wv+64), pre-swizzled source
  const int srow = l >> 2;
  const int scs = (l & 3) ^ ((srow >> 1) & 3);
  auto stage_b = [&](int kk, int bb) {
#pragma unroll
    for (int p = 0; p < 4; ++p) {
      const int rowblk = (wv << 6) + (p << 4);
      const unsigned short* src = &Wp[(rowblk + srow) * DI + (kk << 5) + (scs << 3)];
#ifdef HAVE_GLDS
      gl2lds16(src, &sB[bb][rowblk << 5]);
#else
      *(u16x8*)&sB[bb][(rowblk << 5) + l * 8] = *(const u16x8*)src;
#endif
    }
  };

  // ---- phase A: X tile -> LDS (bf16) ----
  stage_b(0, 0);                               // W(0) in flight under X loads
  {
    const int xrow = tid >> 3;                 // 0..63
    const int ci = tid & 7;                    // chunk interleave lane
    const float* xp = &X[(rowbase + xrow) * DI];
#pragma unroll
    for (int i = 0; i < 8; ++i) {
      const int c_abs = ci + (i << 3);         // 8-chunk stride: coalesced
      f32x4 v0 = *(const f32x4*)(xp + c_abs * 8);
      f32x4 v1 = *(const f32x4*)(xp + c_abs * 8 + 4);
      u16x8 h;
      h[0] = f2bf(v0[0]); h[1] = f2bf(v0[1]); h[2] = f2bf(v0[2]); h[3] = f2bf(v0[3]);
      h[4] = f2bf(v1[0]); h[5] = f2bf(v1[1]); h[6] = f2bf(v1[2]); h[7] = f2bf(v1[3]);
      *(u16x8*)&sX[xrow * SXS + c_abs * 8] = h;
    }
  }
  __syncthreads();

  // ---- phase B: k-loop, W-only staging ----
  f32x4 acc[2][8] = {};
  for (int k = 0; k < 16; ++k) {
    const int buf = k & 1;
    if (k < 15) stage_b(k + 1, buf ^ 1);
    bf16x8 a[2], b[8];
#pragma unroll
    for (int mf = 0; mf < 2; ++mf)
      a[mf] = *(const bf16x8*)&sX[((wm << 5) + (mf << 4) + lm) * SXS + (k << 5) + (lk << 3)];
#pragma unroll
    for (int nf = 0; nf < 8; ++nf)
      b[nf] = *(const bf16x8*)&sB[buf][(((wn << 7) + (nf << 4) + lm) << 5) + (ck << 3)];
#pragma unroll
    for (int mf = 0; mf < 2; ++mf)
#pragma unroll
      for (int nf = 0; nf < 8; ++nf)
        acc[mf][nf] = MFMA16(b[nf], a[mf], acc[mf][nf]);
    __syncthreads();
  }

  // epilogue: lane holds out[gm][gn..gn+3] per (mf,nf)
#pragma unroll
  for (int mf = 0; mf < 2; ++mf) {
    const int gm = rowbase + (wm << 5) + (mf << 4) + lm;
#pragma unroll
    for (int nf = 0; nf < 8; ++nf) {
      const int gn = (wn << 7) + (nf << 4) + (lk << 2);
      *(f32x4*)&out[gm * DI + gn] = acc[mf][nf];
    }
  }
}

extern "C" void kernel_launch(void* const* d_in, const int* in_sizes, int n_in,
                              void* d_out, int out_size, void* d_ws, size_t ws_size,
                              hipStream_t stream) {
  const float* X = (const float*)d_in[0];
  const float* W = (const float*)d_in[1];
  float* out = (float*)d_out;

  char* ws = (char*)d_ws;
  size_t off = 0;
  auto carve = [&](size_t bytes) { void* p = ws + off; off += (bytes + 255) & ~(size_t)255; return p; };

  const size_t F32 = (size_t)DI * DI * 4;
  const size_t BF  = (size_t)DI * DI * 2;

  float* Wm[2];           unsigned short *Wh[2], *Wl[2], *WTh[2], *WTl[2];
  Wm[0]  = (float*)carve(F32);          Wm[1]  = (float*)carve(F32);
  Wh[0]  = (unsigned short*)carve(BF);  Wh[1]  = (unsigned short*)carve(BF);
  Wl[0]  = (unsigned short*)carve(BF);  Wl[1]  = (unsigned short*)carve(BF);
  WTh[0] = (unsigned short*)carve(BF);  WTh[1] = (unsigned short*)carve(BF);
  WTl[0] = (unsigned short*)carve(BF);  WTl[1] = (unsigned short*)carve(BF);
  unsigned short* Gh = (unsigned short*)carve(BF);
  unsigned short* Gl = (unsigned short*)carve(BF);

  k_split<<<1024, 256, 0, stream>>>(W, Wm[0], Wh[0], Wl[0], WTh[0], WTl[0]);

  int cur = 0;
  for (int it = 0; it < 10; ++it) {
    // G = W^T W  (NT on transposed-W arrays)
    k_mm2<<<512, 256, 0, stream>>>(WTh[cur], WTl[cur], WTh[cur], WTl[cur], 0,
                                   nullptr, nullptr, Gh, Gl, nullptr, nullptr);
    const int nxt = cur ^ 1;
    // Wnew = 1.5 W - 0.5 W G   (G symmetric); final iter: only Wh
    k_mm2<<<512, 256, 0, stream>>>(Wh[cur], Wl[cur], Gh, Gl, (it == 9) ? 2 : 1,
                                   Wm[cur], Wm[nxt], Wh[nxt], Wl[nxt], WTh[nxt], WTl[nxt]);
    cur = nxt;
  }

  k_big<<<2048, 512, 0, stream>>>(X, Wh[cur], out);
}

// Round 9
// 423.135 us; speedup vs baseline: 1.0141x; 1.0141x over previous
//
#include <hip/hip_runtime.h>

// BjorckLinear: out = X @ bjorck10(W)^T
//   X: [131072, 512] f32, W: [512, 512] f32, out: [131072, 512] f32
//
// R9: k_big with ZERO k-loop barriers: X tile staged once to LDS (bf16,
//     padded stride, conflict-free), W fragments read directly from L2 into
//     VGPRs (no LDS-W, no __syncthreads, no vmcnt(0) drains) -> waves drift,
//     compiler pipelines loads across unrolled k-steps; 66.5 KB LDS ->
//     2 blocks/CU so phase A / compute / epilogue overlap across blocks.
//     Bjorck: unchanged proven 20-launch k_mm2 (~10us/slot).

using bf16x8 = __attribute__((ext_vector_type(8))) short;
using f32x4  = __attribute__((ext_vector_type(4))) float;
using u16x8  = __attribute__((ext_vector_type(8))) unsigned short;

#define DI 512
#define MFMA16(a, b, c) __builtin_amdgcn_mfma_f32_16x16x32_bf16(a, b, c, 0, 0, 0)
#define SXS 520   // sX row stride (bf16): bank quad = (row + chunk) % 8 -> uniform

__device__ __forceinline__ unsigned short f2bf(float f) {
  unsigned int u = __builtin_bit_cast(unsigned int, f);
  u += 0x7FFFu + ((u >> 16) & 1u);   // RNE
  return (unsigned short)(u >> 16);
}
__device__ __forceinline__ float bf2f(unsigned short h) {
  unsigned int u = ((unsigned int)h) << 16;
  return __builtin_bit_cast(float, u);
}

// ---- initial split: W f32 -> f32 master + hi/lo bf16 (+ transposed) ----
__global__ void k_split(const float* __restrict__ W, float* __restrict__ Wm,
                        unsigned short* __restrict__ Wh, unsigned short* __restrict__ Wl,
                        unsigned short* __restrict__ WTh, unsigned short* __restrict__ WTl) {
  int idx = blockIdx.x * blockDim.x + threadIdx.x;
  int m = idx >> 9, i = idx & 511;
  float w = W[idx];
  Wm[idx] = w;
  unsigned short h  = f2bf(w);
  unsigned short lo = f2bf(w - bf2f(h));
  Wh[idx] = h; Wl[idx] = lo;
  WTh[i * DI + m] = h; WTl[i * DI + m] = lo;
}

// ---- 512x512 NT GEMM: wave per (16x16 tile, K-half); LDS pair-reduce ----
// mode 0: C -> hi/lo bf16 (Oh, Ol)
// mode 1: Wnew = 1.5*Wm_in - 0.5*C -> f32 + hi/lo + transposed hi/lo
// mode 2: like mode 1 but writes ONLY Oh (final iteration)
__global__ __launch_bounds__(256) void k_mm2(
    const unsigned short* __restrict__ Ah, const unsigned short* __restrict__ Al,
    const unsigned short* __restrict__ Bh, const unsigned short* __restrict__ Bl,
    int mode,
    const float* __restrict__ Wm_in, float* __restrict__ Wm_out,
    unsigned short* __restrict__ Oh, unsigned short* __restrict__ Ol,
    unsigned short* __restrict__ OTh, unsigned short* __restrict__ OTl) {
  const int tid = threadIdx.x;
  const int l = tid & 63, lw = tid >> 6;
  const int wid = (blockIdx.x << 2) | lw;     // 0..2047
  const int tile = wid >> 1, half = wid & 1;  // 1024 tiles x 2 K-halves
  const int m0 = (tile >> 5) << 4, n0 = (tile & 31) << 4;
  const int kb = half << 8;
  const int lm = l & 15, lk = l >> 4;
  const int ra = (m0 + lm) * DI + kb + (lk << 3);
  const int rb = (n0 + lm) * DI + kb + (lk << 3);

  __shared__ f32x4 red[2][64];
  const int pr = lw >> 1;

  f32x4 a0{}, a1{}, a2{}, a3{}, a4{}, a5{};
#pragma unroll
  for (int k0 = 0; k0 < 256; k0 += 64) {
    bf16x8 ah0 = *(const bf16x8*)&Ah[ra + k0];
    bf16x8 al0 = *(const bf16x8*)&Al[ra + k0];
    bf16x8 bh0 = *(const bf16x8*)&Bh[rb + k0];
    bf16x8 bl0 = *(const bf16x8*)&Bl[rb + k0];
    bf16x8 ah1 = *(const bf16x8*)&Ah[ra + k0 + 32];
    bf16x8 al1 = *(const bf16x8*)&Al[ra + k0 + 32];
    bf16x8 bh1 = *(const bf16x8*)&Bh[rb + k0 + 32];
    bf16x8 bl1 = *(const bf16x8*)&Bl[rb + k0 + 32];
    a0 = MFMA16(ah0, bh0, a0);
    a1 = MFMA16(ah0, bl0, a1);
    a2 = MFMA16(al0, bh0, a2);
    a3 = MFMA16(ah1, bh1, a3);
    a4 = MFMA16(ah1, bl1, a4);
    a5 = MFMA16(al1, bh1, a5);
  }
  f32x4 acc = (a0 + a1) + (a2 + a3) + (a4 + a5);

  if (half) red[pr][l] = acc;
  __syncthreads();
  if (!half) {
    acc += red[pr][l];
    const int r0 = m0 + (lk << 2);
    const int cn = n0 + lm;
#pragma unroll
    for (int r = 0; r < 4; ++r) {
      const int gm = r0 + r, gn = cn;
      const float v = acc[r];
      if (mode == 0) {
        unsigned short h = f2bf(v);
        Oh[gm * DI + gn] = h;
        Ol[gm * DI + gn] = f2bf(v - bf2f(h));
      } else if (mode == 1) {
        const float wn = 1.5f * Wm_in[gm * DI + gn] - 0.5f * v;
        Wm_out[gm * DI + gn] = wn;
        unsigned short h = f2bf(wn), lo = f2bf(wn - bf2f(h));
        Oh[gm * DI + gn] = h;   Ol[gm * DI + gn] = lo;
        OTh[gn * DI + gm] = h;  OTl[gn * DI + gm] = lo;
      } else {   // mode 2: final — only bf16-hi needed by k_big
        const float wn = 1.5f * Wm_in[gm * DI + gn] - 0.5f * v;
        Oh[gm * DI + gn] = f2bf(wn);
      }
    }
  }
}

// ---------------- big GEMM: out = bf16(X) @ Wp^T ----------------
// grid 2048, block 512 (8 waves), BM=64, BN=512 (X read once).
// Phase A: 64x512 X-tile -> LDS bf16 (one barrier, the only one).
// Phase B: 16 k-steps, NO barriers: wave wv owns out cols [64wv,64wv+64);
//          per step 4 W-frag loads direct from L2 + 4 ds_read_b128 + 16 MFMA.
// Swapped MFMA operands -> lane holds out[gm][gn..gn+3] -> dwordx4 stores.
__global__ __launch_bounds__(512, 4) void k_big(
    const float* __restrict__ X, const unsigned short* __restrict__ Wp,
    float* __restrict__ out) {
  __shared__ unsigned short sX[64 * SXS];   // 66.5 KB -> 2 blocks/CU
  const int tid = threadIdx.x;
  const int wv = tid >> 6, l = tid & 63;
  const int lm = l & 15, lk = l >> 4;
  const int rowbase = blockIdx.x << 6;

  // ---- phase A: X tile -> LDS (bf16), conflict-free both sides ----
  {
    const int xrow = tid >> 3;                 // 0..63
    const int ci = tid & 7;
    const float* xp = &X[(rowbase + xrow) * DI];
#pragma unroll
    for (int i = 0; i < 8; ++i) {
      const int c = ci + (i << 3);             // chunk 0..63 (8 bf16 each)
      f32x4 v0 = *(const f32x4*)(xp + c * 8);
      f32x4 v1 = *(const f32x4*)(xp + c * 8 + 4);
      u16x8 h;
      h[0] = f2bf(v0[0]); h[1] = f2bf(v0[1]); h[2] = f2bf(v0[2]); h[3] = f2bf(v0[3]);
      h[4] = f2bf(v1[0]); h[5] = f2bf(v1[1]); h[6] = f2bf(v1[2]); h[7] = f2bf(v1[3]);
      *(u16x8*)&sX[xrow * SXS + c * 8] = h;
    }
  }
  __syncthreads();   // the only barrier in the kernel

  // ---- phase B: barrier-free k-loop ----
  f32x4 acc[4][4] = {};
  const unsigned short* wbase = &Wp[(((wv << 6) + lm) * DI) + (lk << 3)];
#pragma unroll 4
  for (int k = 0; k < 16; ++k) {
    bf16x8 b[4], a[4];
#pragma unroll
    for (int nf = 0; nf < 4; ++nf)
      b[nf] = *(const bf16x8*)&wbase[((nf << 4) * DI) + (k << 5)];
#pragma unroll
    for (int mf = 0; mf < 4; ++mf)
      a[mf] = *(const bf16x8*)&sX[((mf << 4) + lm) * SXS + (k << 5) + (lk << 3)];
#pragma unroll
    for (int mf = 0; mf < 4; ++mf)
#pragma unroll
      for (int nf = 0; nf < 4; ++nf)
        acc[mf][nf] = MFMA16(b[nf], a[mf], acc[mf][nf]);
  }

  // ---- epilogue: lane holds out[gm][gn..gn+3] per (mf,nf) ----
#pragma unroll
  for (int mf = 0; mf < 4; ++mf) {
    const int gm = rowbase + (mf << 4) + lm;
#pragma unroll
    for (int nf = 0; nf < 4; ++nf) {
      const int gn = (wv << 6) + (nf << 4) + (lk << 2);
      *(f32x4*)&out[gm * DI + gn] = acc[mf][nf];
    }
  }
}

extern "C" void kernel_launch(void* const* d_in, const int* in_sizes, int n_in,
                              void* d_out, int out_size, void* d_ws, size_t ws_size,
                              hipStream_t stream) {
  const float* X = (const float*)d_in[0];
  const float* W = (const float*)d_in[1];
  float* out = (float*)d_out;

  char* ws = (char*)d_ws;
  size_t off = 0;
  auto carve = [&](size_t bytes) { void* p = ws + off; off += (bytes + 255) & ~(size_t)255; return p; };

  const size_t F32 = (size_t)DI * DI * 4;
  const size_t BF  = (size_t)DI * DI * 2;

  float* Wm[2];           unsigned short *Wh[2], *Wl[2], *WTh[2], *WTl[2];
  Wm[0]  = (float*)carve(F32);          Wm[1]  = (float*)carve(F32);
  Wh[0]  = (unsigned short*)carve(BF);  Wh[1]  = (unsigned short*)carve(BF);
  Wl[0]  = (unsigned short*)carve(BF);  Wl[1]  = (unsigned short*)carve(BF);
  WTh[0] = (unsigned short*)carve(BF);  WTh[1] = (unsigned short*)carve(BF);
  WTl[0] = (unsigned short*)carve(BF);  WTl[1] = (unsigned short*)carve(BF);
  unsigned short* Gh = (unsigned short*)carve(BF);
  unsigned short* Gl = (unsigned short*)carve(BF);

  k_split<<<1024, 256, 0, stream>>>(W, Wm[0], Wh[0], Wl[0], WTh[0], WTl[0]);

  int cur = 0;
  for (int it = 0; it < 10; ++it) {
    // G = W^T W  (NT on transposed-W arrays)
    k_mm2<<<512, 256, 0, stream>>>(WTh[cur], WTl[cur], WTh[cur], WTl[cur], 0,
                                   nullptr, nullptr, Gh, Gl, nullptr, nullptr);
    const int nxt = cur ^ 1;
    // Wnew = 1.5 W - 0.5 W G   (G symmetric); final iter: only Wh
    k_mm2<<<512, 256, 0, stream>>>(Wh[cur], Wl[cur], Gh, Gl, (it == 9) ? 2 : 1,
                                   Wm[cur], Wm[nxt], Wh[nxt], Wl[nxt], WTh[nxt], WTl[nxt]);
    cur = nxt;
  }

  k_big<<<2048, 512, 0, stream>>>(X, Wh[cur], out);
}

// Round 10
// 402.839 us; speedup vs baseline: 1.0651x; 1.0504x over previous
//
#include <hip/hip_runtime.h>

// BjorckLinear: out = X @ bjorck10(W)^T
//   X: [131072, 512] f32, W: [512, 512] f32, out: [131072, 512] f32
//
// R10: (a) Bjorck: proven 20-launch k_mm2, minus the f32 W-master (reconstruct
//      from hi+lo; removes 2MB/iter L2 traffic). Launch-gap-bound, accepted.
//      (b) k_big: T14 async-stage on the R4 layout — single-buffer LDS (36KB),
//      reg-staged W+X issued BEFORE compute(k); raw s_barrier pair per step:
//      barrier-1 waits lgkmcnt(0) ONLY (global loads stay in flight under the
//      32-MFMA phase), vmcnt(0) just before the LDS writes, barrier-2
//      publishes. Nontemporal stores for out (streaming).

using bf16x8 = __attribute__((ext_vector_type(8))) short;
using f32x4  = __attribute__((ext_vector_type(4))) float;
using u16x8  = __attribute__((ext_vector_type(8))) unsigned short;

#define DI 512
#define MFMA16(a, b, c) __builtin_amdgcn_mfma_f32_16x16x32_bf16(a, b, c, 0, 0, 0)

__device__ __forceinline__ unsigned short f2bf(float f) {
  unsigned int u = __builtin_bit_cast(unsigned int, f);
  u += 0x7FFFu + ((u >> 16) & 1u);   // RNE
  return (unsigned short)(u >> 16);
}
__device__ __forceinline__ float bf2f(unsigned short h) {
  unsigned int u = ((unsigned int)h) << 16;
  return __builtin_bit_cast(float, u);
}

// ---- initial split: W f32 -> hi/lo bf16 (+ transposed) ----
__global__ void k_split(const float* __restrict__ W,
                        unsigned short* __restrict__ Wh, unsigned short* __restrict__ Wl,
                        unsigned short* __restrict__ WTh, unsigned short* __restrict__ WTl) {
  int idx = blockIdx.x * blockDim.x + threadIdx.x;
  int m = idx >> 9, i = idx & 511;
  float w = W[idx];
  unsigned short h  = f2bf(w);
  unsigned short lo = f2bf(w - bf2f(h));
  Wh[idx] = h; Wl[idx] = lo;
  WTh[i * DI + m] = h; WTl[i * DI + m] = lo;
}

// ---- 512x512 NT GEMM: wave per (16x16 tile, K-half); LDS pair-reduce ----
// mode 0: C -> hi/lo bf16 (Oh, Ol)
// mode 1: Wnew = 1.5*(Ah+Al at output idx) - 0.5*C -> hi/lo + transposed hi/lo
// mode 2: like mode 1 but writes ONLY Oh (final iteration)
__global__ __launch_bounds__(256) void k_mm2(
    const unsigned short* __restrict__ Ah, const unsigned short* __restrict__ Al,
    const unsigned short* __restrict__ Bh, const unsigned short* __restrict__ Bl,
    int mode,
    unsigned short* __restrict__ Oh, unsigned short* __restrict__ Ol,
    unsigned short* __restrict__ OTh, unsigned short* __restrict__ OTl) {
  const int tid = threadIdx.x;
  const int l = tid & 63, lw = tid >> 6;
  const int wid = (blockIdx.x << 2) | lw;     // 0..2047
  const int tile = wid >> 1, half = wid & 1;  // 1024 tiles x 2 K-halves
  const int m0 = (tile >> 5) << 4, n0 = (tile & 31) << 4;
  const int kb = half << 8;
  const int lm = l & 15, lk = l >> 4;
  const int ra = (m0 + lm) * DI + kb + (lk << 3);
  const int rb = (n0 + lm) * DI + kb + (lk << 3);

  __shared__ f32x4 red[2][64];
  const int pr = lw >> 1;

  f32x4 a0{}, a1{}, a2{}, a3{}, a4{}, a5{};
#pragma unroll
  for (int k0 = 0; k0 < 256; k0 += 64) {
    bf16x8 ah0 = *(const bf16x8*)&Ah[ra + k0];
    bf16x8 al0 = *(const bf16x8*)&Al[ra + k0];
    bf16x8 bh0 = *(const bf16x8*)&Bh[rb + k0];
    bf16x8 bl0 = *(const bf16x8*)&Bl[rb + k0];
    bf16x8 ah1 = *(const bf16x8*)&Ah[ra + k0 + 32];
    bf16x8 al1 = *(const bf16x8*)&Al[ra + k0 + 32];
    bf16x8 bh1 = *(const bf16x8*)&Bh[rb + k0 + 32];
    bf16x8 bl1 = *(const bf16x8*)&Bl[rb + k0 + 32];
    a0 = MFMA16(ah0, bh0, a0);
    a1 = MFMA16(ah0, bl0, a1);
    a2 = MFMA16(al0, bh0, a2);
    a3 = MFMA16(ah1, bh1, a3);
    a4 = MFMA16(ah1, bl1, a4);
    a5 = MFMA16(al1, bh1, a5);
  }
  f32x4 acc = (a0 + a1) + (a2 + a3) + (a4 + a5);

  if (half) red[pr][l] = acc;
  __syncthreads();
  if (!half) {
    acc += red[pr][l];
    const int r0 = m0 + (lk << 2);
    const int cn = n0 + lm;
#pragma unroll
    for (int r = 0; r < 4; ++r) {
      const int gm = r0 + r, gn = cn;
      const float v = acc[r];
      if (mode == 0) {
        unsigned short h = f2bf(v);
        Oh[gm * DI + gn] = h;
        Ol[gm * DI + gn] = f2bf(v - bf2f(h));
      } else {
        // W_cur value from hi+lo (replaces f32 master; error ~2^-17 rel)
        const float wcur = bf2f(Ah[gm * DI + gn]) + bf2f(Al[gm * DI + gn]);
        const float wn = 1.5f * wcur - 0.5f * v;
        if (mode == 1) {
          unsigned short h = f2bf(wn), lo = f2bf(wn - bf2f(h));
          Oh[gm * DI + gn] = h;   Ol[gm * DI + gn] = lo;
          OTh[gn * DI + gm] = h;  OTl[gn * DI + gm] = lo;
        } else {
          Oh[gm * DI + gn] = f2bf(wn);
        }
      }
    }
  }
}

// ---------------- big GEMM: out = bf16(X) @ Wp^T ----------------
// grid 2048, block 256 (4 waves), BM=64, BN=512 (X read once), BK=32.
// Single-buffer LDS (36KB -> LDS-side 4 blocks/CU; regs cap at 2).
// Per k-step: issue reg-loads(k+1) -> compute(k) -> [lgkmcnt(0); barrier]
// -> vmcnt(0); LDS writes -> [lgkmcnt(0); barrier].  Global-load latency is
// covered by the 32-MFMA phase, never drained before it.
__global__ __launch_bounds__(256, 2) void k_big(
    const float* __restrict__ X, const unsigned short* __restrict__ Wp,
    float* __restrict__ out) {
  __shared__ unsigned short sX[2048];     // 64 rows x 32 k (chunk-swizzled)
  __shared__ unsigned short sB[16384];    // 512 rows x 32 k
  const int tid = threadIdx.x;
  const int w = tid >> 6, l = tid & 63;
  const int lm = l & 15, lk = l >> 4;
  const int ck = lk ^ ((lm >> 1) & 3);      // swizzled read chunk
  const int rowbase = blockIdx.x << 6;

  // X staging coords (thread t: row t>>2, chunk t&3)
  const int arow = tid >> 2, ac = tid & 3;
  const int alds = (arow * 4 + (ac ^ ((arow >> 1) & 3))) * 8;
  const float* xsrc = &X[(rowbase + arow) * DI + (ac << 3)];

  // W staging coords: wave w covers rows [ph*64 + w*16, +16), thread row l>>2,
  // pre-swizzled source chunk; LDS dest = rowblk base + l*8 (glds-style layout)
  const int brow_l = l >> 2;
  const int bcs = (l & 3) ^ ((brow_l >> 1) & 3);

  f32x4 acc[4][8] = {};
  f32x4 xr0, xr1;
  u16x8 wr[8];

  auto issue = [&](int kk) {
    xr0 = *(const f32x4*)(xsrc + (kk << 5));
    xr1 = *(const f32x4*)(xsrc + (kk << 5) + 4);
#pragma unroll
    for (int ph = 0; ph < 8; ++ph) {
      const int rowblk = ph * 64 + w * 16;
      wr[ph] = *(const u16x8*)&Wp[(rowblk + brow_l) * DI + (kk << 5) + (bcs << 3)];
    }
  };
  auto publish = [&]() {
    u16x8 h;
    h[0] = f2bf(xr0[0]); h[1] = f2bf(xr0[1]); h[2] = f2bf(xr0[2]); h[3] = f2bf(xr0[3]);
    h[4] = f2bf(xr1[0]); h[5] = f2bf(xr1[1]); h[6] = f2bf(xr1[2]); h[7] = f2bf(xr1[3]);
    *(u16x8*)&sX[alds] = h;
#pragma unroll
    for (int ph = 0; ph < 8; ++ph)
      *(u16x8*)&sB[(ph * 64 + w * 16) * 32 + l * 8] = wr[ph];
  };

  // prologue
  issue(0);
  asm volatile("s_waitcnt vmcnt(0)" ::: "memory");
  publish();
  asm volatile("s_waitcnt lgkmcnt(0)" ::: "memory");
  __builtin_amdgcn_s_barrier();

  for (int k = 0; k < 16; ++k) {
    if (k < 15) issue(k + 1);                 // loads in flight under compute
    bf16x8 a[4], b[8];
#pragma unroll
    for (int mf = 0; mf < 4; ++mf)
      a[mf] = *(const bf16x8*)&sX[((mf * 16 + lm) * 4 + ck) * 8];
#pragma unroll
    for (int nf = 0; nf < 8; ++nf)
      b[nf] = *(const bf16x8*)&sB[((w * 128 + nf * 16 + lm) * 4 + ck) * 8];
#pragma unroll
    for (int mf = 0; mf < 4; ++mf)
#pragma unroll
      for (int nf = 0; nf < 8; ++nf)
        acc[mf][nf] = MFMA16(b[nf], a[mf], acc[mf][nf]);
    if (k < 15) {
      asm volatile("s_waitcnt lgkmcnt(0)" ::: "memory");  // ds_reads done; vm stays in flight
      __builtin_amdgcn_s_barrier();
      asm volatile("s_waitcnt vmcnt(0)" ::: "memory");    // covered by MFMA phase
      publish();
      asm volatile("s_waitcnt lgkmcnt(0)" ::: "memory");
      __builtin_amdgcn_s_barrier();
    }
  }

  // epilogue: lane holds out[gm][gn..gn+3] per (mf,nf); nontemporal stream
#pragma unroll
  for (int mf = 0; mf < 4; ++mf) {
    const int gm = rowbase + (mf << 4) + lm;
#pragma unroll
    for (int nf = 0; nf < 8; ++nf) {
      const int gn = (w << 7) + (nf << 4) + (lk << 2);
      __builtin_nontemporal_store(acc[mf][nf], (f32x4*)&out[gm * DI + gn]);
    }
  }
}

extern "C" void kernel_launch(void* const* d_in, const int* in_sizes, int n_in,
                              void* d_out, int out_size, void* d_ws, size_t ws_size,
                              hipStream_t stream) {
  const float* X = (const float*)d_in[0];
  const float* W = (const float*)d_in[1];
  float* out = (float*)d_out;

  char* ws = (char*)d_ws;
  size_t off = 0;
  auto carve = [&](size_t bytes) { void* p = ws + off; off += (bytes + 255) & ~(size_t)255; return p; };

  const size_t BF = (size_t)DI * DI * 2;

  unsigned short *Wh[2], *Wl[2], *WTh[2], *WTl[2];
  Wh[0]  = (unsigned short*)carve(BF);  Wh[1]  = (unsigned short*)carve(BF);
  Wl[0]  = (unsigned short*)carve(BF);  Wl[1]  = (unsigned short*)carve(BF);
  WTh[0] = (unsigned short*)carve(BF);  WTh[1] = (unsigned short*)carve(BF);
  WTl[0] = (unsigned short*)carve(BF);  WTl[1] = (unsigned short*)carve(BF);
  unsigned short* Gh = (unsigned short*)carve(BF);
  unsigned short* Gl = (unsigned short*)carve(BF);

  k_split<<<1024, 256, 0, stream>>>(W, Wh[0], Wl[0], WTh[0], WTl[0]);

  int cur = 0;
  for (int it = 0; it < 10; ++it) {
    // G = W^T W  (NT on transposed-W arrays)
    k_mm2<<<512, 256, 0, stream>>>(WTh[cur], WTl[cur], WTh[cur], WTl[cur], 0,
                                   Gh, Gl, nullptr, nullptr);
    const int nxt = cur ^ 1;
    // Wnew = 1.5 W - 0.5 W G  (G symmetric); final iter writes only Wh
    k_mm2<<<512, 256, 0, stream>>>(Wh[cur], Wl[cur], Gh, Gl, (it == 9) ? 2 : 1,
                                   Wh[nxt], Wl[nxt], WTh[nxt], WTl[nxt]);
    cur = nxt;
  }

  k_big<<<2048, 256, 0, stream>>>(X, Wh[cur], out);
}